// Round 5
// baseline (551.194 us; speedup 1.0000x reference)
//
#include <hip/hip_runtime.h>
#include <hip/hip_bf16.h>
#include <math.h>

// B=32, S=1, DIM=2048, NH=32, NKV=8, HD=64, L=2048, START_POS=2047.
// Inputs float32. OUTPUT float32 (reference is pure jnp.float32 —
// rounds 2-4 failed only because we wrote bf16 into an f32 buffer).
#define NQKV 3072

__device__ __forceinline__ int read_sp(const int* spp) {
  if (!spp) return 2047;
  int raw = spp[0];
  if (raw >= 0 && raw < 2048) return raw;
  union { int i; float f; } u; u.i = raw;
  if (u.f >= 0.f && u.f < 2048.f) return (int)u.f;
  return 2047;
}

// ---------------- K0: x (f32 [32][2048]) -> xt (f32 [2048][32]) transposed
__global__ __launch_bounds__(256) void k_prep(const float* __restrict__ x,
                                              float* __restrict__ xt) {
  int idx = blockIdx.x * 256 + threadIdx.x;   // 65536 total
  int r = idx >> 11, k = idx & 2047;
  xt[k * 32 + r] = x[idx];
}

// ---------------- K1: QKV partial GEMM: part[j][32][3072]
__global__ __launch_bounds__(256) void k_qkv(const float* __restrict__ qw,
                                             const float* __restrict__ kw,
                                             const float* __restrict__ vw,
                                             const float* __restrict__ xt,
                                             float* __restrict__ part, int kc) {
  int colb = blockIdx.x, j = blockIdx.y;
  int n = colb * 256 + threadIdx.x;
  const float* w; int ldw, nn;
  if (colb < 8)       { w = qw; ldw = 2048; nn = n; }
  else if (colb < 10) { w = kw; ldw = 512;  nn = n - 2048; }
  else                { w = vw; ldw = 512;  nn = n - 2560; }
  int k0 = j * kc;
  const float* wp = w + (size_t)k0 * ldw + nn;
  float acc[32];
  #pragma unroll
  for (int r = 0; r < 32; r++) acc[r] = 0.f;
  #pragma unroll 2
  for (int kk = 0; kk < kc; kk++) {
    float wv = wp[(size_t)kk * ldw];
    const float* xr = xt + (size_t)(k0 + kk) * 32;
    #pragma unroll
    for (int r = 0; r < 32; r++) acc[r] = fmaf(xr[r], wv, acc[r]);
  }
  float* po = part + (size_t)j * 32 * NQKV + n;
  #pragma unroll
  for (int r = 0; r < 32; r++) po[(size_t)r * NQKV] = acc[r];
}

// ---------------- K2: attention. grid (8 kv-heads, 32 batches), 1024 threads.
__global__ __launch_bounds__(1024) void k_attn(const float* __restrict__ ck,
                                               const float* __restrict__ cv,
                                               const float* __restrict__ part,
                                               float* __restrict__ obt,
                                               const int* __restrict__ spp,
                                               int ks) {
  int h = blockIdx.x, b = blockIdx.y, tid = threadIdx.x;
  int sp = read_sp(spp);                 // 2047; L = sp+1 = 2048

  __shared__ float qraw[384];
  __shared__ __align__(16) float qs[4][64];
  __shared__ float knew[64];
  __shared__ float vnew[64];
  __shared__ __align__(16) float sc[4][2048];
  __shared__ float wred[16];
  __shared__ float mfin[4];
  __shared__ float inv_[4];
  __shared__ __align__(16) float opart[4][4][64];

  // stage 1: reduce the ks K-split partials for this block's 384 columns
  if (tid < 384) {
    int col;
    if (tid < 256)      col = h * 256 + tid;                 // 4 q heads
    else if (tid < 320) col = 2048 + h * 64 + (tid - 256);   // k
    else                col = 2560 + h * 64 + (tid - 320);   // v
    float s = 0.f;
    for (int j = 0; j < ks; j++) s += part[(size_t)(j * 32 + b) * NQKV + col];
    qraw[tid] = s;
  }
  __syncthreads();

  // stage 2: RoPE (f64 angles) on q (1/8 scale folded) + new k; copy new v
  if (tid < 160) {
    int rr = tid >> 5, i = tid & 31;
    double freq = pow(10000.0, -(double)(2 * i) / 64.0);
    double ang = (double)sp * freq;
    double sd, cd; sincos(ang, &sd, &cd);
    float sn = (float)sd, cs = (float)cd;
    if (rr < 4) {
      float a = qraw[rr * 64 + 2 * i], bq = qraw[rr * 64 + 2 * i + 1];
      qs[rr][2 * i]     = (a * cs - bq * sn) * 0.125f;
      qs[rr][2 * i + 1] = (a * sn + bq * cs) * 0.125f;
    } else {
      float a = qraw[256 + 2 * i], bk = qraw[256 + 2 * i + 1];
      knew[2 * i]     = a * cs - bk * sn;
      knew[2 * i + 1] = a * sn + bk * cs;
    }
  } else if (tid < 224) {
    vnew[tid - 160] = qraw[320 + (tid - 160)];
  }
  __syncthreads();

  // pass 1: scores. thread group r (256 threads) handles rep head r.
  int r = tid >> 8;
  int t = tid & 255;
  float qv[64];
  #pragma unroll
  for (int d4 = 0; d4 < 16; d4++) {
    float4 v = *(const float4*)&qs[r][d4 * 4];
    qv[d4 * 4 + 0] = v.x; qv[d4 * 4 + 1] = v.y;
    qv[d4 * 4 + 2] = v.z; qv[d4 * 4 + 3] = v.w;
  }
  const float* kb = ck + ((size_t)b * 2048 * 8 + h) * 64;
  float lmax = -1e30f;
  #pragma unroll 2
  for (int jj = 0; jj < 8; jj++) {
    int p = jj * 256 + t;
    float s = 0.f;
    if (p != sp) {
      const float4* kp = (const float4*)(kb + (size_t)p * 512);
      #pragma unroll
      for (int c = 0; c < 16; c++) {
        float4 u = kp[c];
        s = fmaf(qv[c * 4 + 0], u.x, s); s = fmaf(qv[c * 4 + 1], u.y, s);
        s = fmaf(qv[c * 4 + 2], u.z, s); s = fmaf(qv[c * 4 + 3], u.w, s);
      }
    } else {
      #pragma unroll
      for (int d = 0; d < 64; d++) s = fmaf(qv[d], knew[d], s);
    }
    lmax = fmaxf(lmax, s);
    sc[r][p] = s;
  }

  // softmax: max then sum-exp (per rep head r; its 4 waves are 4r..4r+3)
  #pragma unroll
  for (int off = 32; off > 0; off >>= 1) lmax = fmaxf(lmax, __shfl_xor(lmax, off));
  int w = tid >> 6;
  if ((tid & 63) == 0) wred[w] = lmax;
  __syncthreads();
  if (tid < 4)
    mfin[tid] = fmaxf(fmaxf(wred[tid * 4 + 0], wred[tid * 4 + 1]),
                      fmaxf(wred[tid * 4 + 2], wred[tid * 4 + 3]));
  __syncthreads();
  float m = mfin[r];
  float lsum = 0.f;
  #pragma unroll
  for (int jj = 0; jj < 8; jj++) {
    float e = __expf(sc[r][jj * 256 + t] - m);
    lsum += e;
    sc[r][jj * 256 + t] = e;
  }
  #pragma unroll
  for (int off = 32; off > 0; off >>= 1) lsum += __shfl_xor(lsum, off);
  if ((tid & 63) == 0) wred[w] = lsum;
  __syncthreads();
  if (tid < 4)
    inv_[tid] = 1.0f / (wred[tid * 4 + 0] + wred[tid * 4 + 1] +
                        wred[tid * 4 + 2] + wred[tid * 4 + 3]);
  __syncthreads();

  // pass 2: o[r][d] = sum_p e[r][p] * v[p][d]. wave = fixed (g,r2), lanes = d.
  int g = tid >> 8;
  int r2 = (tid >> 6) & 3;
  int d = tid & 63;
  const float* vb = cv + ((size_t)b * 2048 * 8 + h) * 64 + d;
  float acc = 0.f;
  int p0 = g * 512;
  #pragma unroll 2
  for (int p4 = p0; p4 < p0 + 512; p4 += 4) {
    float4 e4 = *(const float4*)&sc[r2][p4];
    float v0 = (p4 + 0 == sp) ? vnew[d] : vb[(size_t)(p4 + 0) * 512];
    float v1 = (p4 + 1 == sp) ? vnew[d] : vb[(size_t)(p4 + 1) * 512];
    float v2 = (p4 + 2 == sp) ? vnew[d] : vb[(size_t)(p4 + 2) * 512];
    float v3 = (p4 + 3 == sp) ? vnew[d] : vb[(size_t)(p4 + 3) * 512];
    acc = fmaf(e4.x, v0, acc); acc = fmaf(e4.y, v1, acc);
    acc = fmaf(e4.z, v2, acc); acc = fmaf(e4.w, v3, acc);
  }
  opart[g][r2][d] = acc;
  __syncthreads();
  if (tid < 256) {
    int rr = tid >> 6, dd = tid & 63;
    float o = (opart[0][rr][dd] + opart[1][rr][dd] +
               opart[2][rr][dd] + opart[3][rr][dd]) * inv_[rr];
    int col = (h * 4 + rr) * 64 + dd;
    obt[(size_t)col * 32 + b] = o;                 // transposed for k_oproj
  }
}

// ---------------- K3: O partial GEMM: part[j][32][2048] (aliases part_qkv)
__global__ __launch_bounds__(256) void k_oproj(const float* __restrict__ ow,
                                               const float* __restrict__ obt,
                                               float* __restrict__ part, int kc) {
  int colb = blockIdx.x, j = blockIdx.y;
  int n = colb * 256 + threadIdx.x;
  int k0 = j * kc;
  const float* wp = ow + (size_t)k0 * 2048 + n;
  float acc[32];
  #pragma unroll
  for (int r = 0; r < 32; r++) acc[r] = 0.f;
  #pragma unroll 2
  for (int kk = 0; kk < kc; kk++) {
    float wv = wp[(size_t)kk * 2048];
    const float* xr = obt + (size_t)(k0 + kk) * 32;
    #pragma unroll
    for (int r = 0; r < 32; r++) acc[r] = fmaf(xr[r], wv, acc[r]);
  }
  float* po = part + (size_t)j * 32 * 2048 + n;
  #pragma unroll
  for (int r = 0; r < 32; r++) po[(size_t)r * 2048] = acc[r];
}

// ---------------- K4: reduce K-split partials -> f32 output
__global__ __launch_bounds__(256) void k_finish(const float* __restrict__ part,
                                                float* __restrict__ out, int ks) {
  int idx = blockIdx.x * 256 + threadIdx.x;  // 65536 = 32*2048, b*2048+n
  float s = 0.f;
  for (int j = 0; j < ks; j++) s += part[(size_t)j * 65536 + idx];
  out[idx] = s;                              // FLOAT32 output
}

extern "C" void kernel_launch(void* const* d_in, const int* in_sizes, int n_in,
                              void* d_out, int out_size, void* d_ws, size_t ws_size,
                              hipStream_t stream) {
  const float* x  = (const float*)d_in[0];
  const float* qw = (const float*)d_in[1];
  const float* kw = (const float*)d_in[2];
  const float* vw = (const float*)d_in[3];
  const float* ow = (const float*)d_in[4];
  const float* ck = (const float*)d_in[5];
  const float* cv = (const float*)d_in[6];
  const int*   sp = (n_in >= 8) ? (const int*)d_in[7] : nullptr;

  // Pick K-split so workspace fits: (131072 + ks*98304) f32.
  int ks = 1;
  {
    const int cands[4] = {16, 8, 4, 2};
    for (int i = 0; i < 4; i++) {
      if ((size_t)(131072 + (size_t)cands[i] * 98304) * 4 <= ws_size) { ks = cands[i]; break; }
    }
  }
  int kc = 2048 / ks;

  float* ws   = (float*)d_ws;
  float* xt   = ws;                          // 65536 f32
  float* part = xt + 65536;                  // ks*98304 f32 (QKV partials)
  float* obt  = part + (size_t)ks * 98304;   // 65536 f32
  float* part_out = part;                    // reuse after k_attn

  k_prep  <<<256,          256,  0, stream>>>(x, xt);
  k_qkv   <<<dim3(12, ks), 256,  0, stream>>>(qw, kw, vw, xt, part, kc);
  k_attn  <<<dim3(8, 32),  1024, 0, stream>>>(ck, cv, part, obt, sp, ks);
  k_oproj <<<dim3(8, ks),  256,  0, stream>>>(ow, obt, part_out, kc);
  k_finish<<<256,          256,  0, stream>>>(part_out, (float*)d_out, ks);
}